// Round 1
// baseline (239.294 us; speedup 1.0000x reference)
//
#include <hip/hip_runtime.h>

// ---------------------------------------------------------------------------
// LengthRegulator — output-centric gather formulation (R6):
//   x   [B, T, C]  float32
//   dur [B, T]     int32
//   out [B, T_out, C]; out[b,t,:] = x[b, idx, :],
//     idx = upper_bound(cumsum(max(dur,0))[b,:], t) clamped to T-1.
//   T_out recovered from out_size: T_out = out_size / (B*C).
//
// Kernel 1: per-row inclusive cumsum of dur -> cum (B*T ints in d_ws).
// Kernel 2: one 256-thread block per FPB=64 consecutive OUTPUT frames of a
//   batch row. cum row staged in LDS (2 KB); 64 threads do a branchless
//   9-step rank search (count of cum <= t, naturally saturating at T-1, so
//   the clamp tail needs no special case); then 32 independent iterations
//   each load a 2 KB x row (L1-cached across the ~5.5-frame runs) and
//   nontemporal-store 2 output frames.
// Rationale vs R5 source-centric scatter (~100 us): spans are data-dependent
//   (dur 0..11) -> serial span walk + idle dur=0 blocks + tail special-case.
//   Gather gives perfectly uniform work and independent (pipelineable)
//   load->store iterations. Ideal traffic ~228 MB => ~36 us floor.
// ---------------------------------------------------------------------------

#define LR_T 512  // tokens per row (fixed by setup_inputs)
#define FPB  64   // output frames per block

// clang vector type: __builtin_nontemporal_* accepts vectors of float,
// but NOT HIP's struct-based float4.
typedef float vfloat4 __attribute__((ext_vector_type(4)));

__global__ void lr_cumsum_kernel(const int* __restrict__ dur,
                                 int* __restrict__ cum, int T) {
    __shared__ int s[LR_T];
    const int b = blockIdx.x;
    const int tid = threadIdx.x;
    int v = dur[(size_t)b * T + tid];
    v = v > 0 ? v : 0;  // jnp.maximum(dur, 0)
    s[tid] = v;
    __syncthreads();
    for (int off = 1; off < LR_T; off <<= 1) {
        int add = (tid >= off) ? s[tid - off] : 0;
        __syncthreads();
        s[tid] += add;
        __syncthreads();
    }
    cum[(size_t)b * T + tid] = s[tid];
}

__global__ void __launch_bounds__(256)
lr_gather_kernel(const vfloat4* __restrict__ x4,
                 const int* __restrict__ cum,
                 vfloat4* __restrict__ out4,
                 int T_out) {
    __shared__ int s_cum[LR_T];
    __shared__ int s_idx[FPB];
    const int tid = threadIdx.x;   // 0..255
    const int b   = blockIdx.y;    // batch row
    const int t0  = blockIdx.x * FPB;

    // Stage this row's cumsum in LDS: 512 ints, two coalesced loads.
    const int* crow = cum + (size_t)b * LR_T;
    s_cum[tid]       = crow[tid];
    s_cum[tid + 256] = crow[tid + 256];
    __syncthreads();

    const int nf = min(FPB, T_out - t0);

    // Branchless rank search: pos = count of cum[j] <= t, saturating at
    // LR_T-1 (sum of steps = 511), which IS the reference's min(idx, T-1).
    if (tid < nf) {
        const int t = t0 + tid;
        int pos = 0;
        #pragma unroll
        for (int s = LR_T / 2; s > 0; s >>= 1)
            pos += (s_cum[pos + s - 1] <= t) ? s : 0;
        s_idx[tid] = pos;
    }
    __syncthreads();

    // 2 output frames per iteration: 128 lanes x 16 B = one 2 KB row each.
    const int lane = tid & 127;    // float4 lane within a C=512 row
    const int half = tid >> 7;     // which frame of the pair
    const vfloat4* __restrict__ xrow = x4 + (size_t)b * LR_T * 128 + lane;
    vfloat4* __restrict__ obase = out4 + ((size_t)b * T_out + t0) * 128 + lane;
    #pragma unroll 4
    for (int f = half; f < nf; f += 2) {
        // Regular (cached) load: runs of ~5.5 frames share one source row,
        // so repeats hit L1. Store is write-once -> nontemporal.
        const vfloat4 v = xrow[(size_t)s_idx[f] * 128];
        __builtin_nontemporal_store(v, obase + (size_t)f * 128);
    }
}

extern "C" void kernel_launch(void* const* d_in, const int* in_sizes, int n_in,
                              void* d_out, int out_size, void* d_ws, size_t ws_size,
                              hipStream_t stream) {
    const float* x   = (const float*)d_in[0];
    const int*   dur = (const int*)d_in[1];
    float*       out = (float*)d_out;

    const int B  = 32;
    const int BT = in_sizes[1];            // B*T
    const int T  = BT / B;                 // 512
    const int C  = in_sizes[0] / BT;       // 512 (row = 128 float4)
    const int T_out = out_size / (B * C);  // data-dependent, encoded in out_size

    int* cum = (int*)d_ws;                 // B*T ints = 64 KB scratch

    lr_cumsum_kernel<<<B, T, 0, stream>>>(dur, cum, T);

    if (T_out > 0) {
        dim3 grid((T_out + FPB - 1) / FPB, B);
        lr_gather_kernel<<<grid, 256, 0, stream>>>(
            (const vfloat4*)x, cum, (vfloat4*)out, T_out);
    }
}